// Round 2
// baseline (126.834 us; speedup 1.0000x reference)
//
#include <hip/hip_runtime.h>
#include <hip/hip_bf16.h>

#define BATCH 32
#define SEQ   2048
#define DIM   64
#define KVB   64
#define NWAVE 4
#define QW    32
#define QB    (NWAVE*QW)   // 128 q-rows per block

typedef __attribute__((ext_vector_type(8))) __bf16 bf16x8;
typedef __attribute__((ext_vector_type(4))) __bf16 bf16x4;
typedef __attribute__((ext_vector_type(2))) __bf16 bf16x2;
typedef __attribute__((ext_vector_type(4))) float  floatx4;

__device__ __forceinline__ float grp16_max(float v) {
    #pragma unroll
    for (int m = 1; m <= 8; m <<= 1) v = fmaxf(v, __shfl_xor(v, m, 64));
    return v;
}
__device__ __forceinline__ float grp16_sum(float v) {
    #pragma unroll
    for (int m = 1; m <= 8; m <<= 1) v += __shfl_xor(v, m, 64);
    return v;
}

__global__ __launch_bounds__(256, 2)
void attn_fwd(const float* __restrict__ Q, const float* __restrict__ K,
              const float* __restrict__ V, float* __restrict__ Out)
{
    // LDS: K tile [kv][d] (swizzled rows of 128B), V^T tile [d][kv] (swizzled),
    // per-wave P [q 32][kv 64] (swizzled). 8 + 8 + 16 = 32 KiB.
    __shared__ __align__(16) __bf16 Kt[KVB * DIM];
    __shared__ __align__(16) __bf16 Vt[DIM * KVB];
    __shared__ __align__(16) __bf16 Pt[NWAVE][QW * KVB];

    const int bid  = blockIdx.x;
    // bijective XCD swizzle: 512 blocks, 8 XCDs -> 64 contiguous logical tiles per XCD
    const int swz  = ((bid & 7) << 6) | (bid >> 3);
    const int b    = swz >> 4;          // batch
    const int q0   = (swz & 15) * QB;   // q-tile start
    const int tid  = threadIdx.x;
    const int w    = tid >> 6;          // wave 0..3
    const int lane = tid & 63;
    const int g    = lane >> 4;         // 0..3
    const int c    = lane & 15;         // 0..15

    char* KtB = reinterpret_cast<char*>(Kt);
    char* VtB = reinterpret_cast<char*>(Vt);
    char* PtB = reinterpret_cast<char*>(&Pt[w][0]);

    // ---- Q fragments, scale 1/sqrt(64)=0.125 folded into the bf16 cast ----
    // A-frag layout: A[m=lane&15][k=(lane>>4)*8+j]; two 16-row m-tiles, two K=32 chunks
    bf16x8 aq[2][2];
    #pragma unroll
    for (int mt = 0; mt < 2; ++mt) {
        const float* qp = Q + ((size_t)(b*SEQ + q0 + w*QW + mt*16 + c))*DIM + g*8;
        #pragma unroll
        for (int kk = 0; kk < 2; ++kk) {
            float4 f0 = *reinterpret_cast<const float4*>(qp + kk*32);
            float4 f1 = *reinterpret_cast<const float4*>(qp + kk*32 + 4);
            bf16x8 a;
            a[0] = (__bf16)(f0.x * 0.125f); a[1] = (__bf16)(f0.y * 0.125f);
            a[2] = (__bf16)(f0.z * 0.125f); a[3] = (__bf16)(f0.w * 0.125f);
            a[4] = (__bf16)(f1.x * 0.125f); a[5] = (__bf16)(f1.y * 0.125f);
            a[6] = (__bf16)(f1.z * 0.125f); a[7] = (__bf16)(f1.w * 0.125f);
            aq[mt][kk] = a;
        }
    }

    floatx4 o[2][4];          // O accum: [m-tile][d-tile], rows = g*4+r, col = c
    float mrun[2][4], lrun[2][4];
    #pragma unroll
    for (int mt = 0; mt < 2; ++mt)
        #pragma unroll
        for (int r = 0; r < 4; ++r) { mrun[mt][r] = -INFINITY; lrun[mt][r] = 0.f; }
    #pragma unroll
    for (int mt = 0; mt < 2; ++mt)
        #pragma unroll
        for (int dt = 0; dt < 4; ++dt) o[mt][dt] = (floatx4){0.f, 0.f, 0.f, 0.f};

    const float* kbase = K + (size_t)b * SEQ * DIM;
    const float* vbase = V + (size_t)b * SEQ * DIM;

    for (int kt = 0; kt < SEQ / KVB; ++kt) {
        __syncthreads();   // previous iteration's LDS reads done before overwrite

        // ---- stage K tile: 64x64 fp32 -> bf16, row-major, XOR-swizzled ----
        {
            const float* kp = kbase + (size_t)kt * KVB * DIM;
            #pragma unroll
            for (int st = 0; st < 4; ++st) {
                int idx = st * 256 + tid;        // float4 granule 0..1023 (coalesced)
                int row = idx >> 4;
                int col = (idx & 15) << 2;       // float col
                float4 f = *reinterpret_cast<const float4*>(kp + row*DIM + col);
                bf16x4 h = {(__bf16)f.x, (__bf16)f.y, (__bf16)f.z, (__bf16)f.w};
                *reinterpret_cast<bf16x4*>(KtB + row*128 + ((col*2) ^ ((row & 7) << 4))) = h;
            }
        }
        // ---- stage V^T tile: read V[kv][d] coalesced, write Vt[d][kv] packed pairs ----
        {
            const float* vp = vbase + (size_t)kt * KVB * DIM;
            int kv0 = (tid >> 3) << 1;
            int d0  = (tid & 7) << 3;
            float4 a0 = *reinterpret_cast<const float4*>(vp + kv0*DIM + d0);
            float4 a1 = *reinterpret_cast<const float4*>(vp + kv0*DIM + d0 + 4);
            float4 b0 = *reinterpret_cast<const float4*>(vp + (kv0+1)*DIM + d0);
            float4 b1 = *reinterpret_cast<const float4*>(vp + (kv0+1)*DIM + d0 + 4);
            float av[8] = {a0.x,a0.y,a0.z,a0.w,a1.x,a1.y,a1.z,a1.w};
            float bv[8] = {b0.x,b0.y,b0.z,b0.w,b1.x,b1.y,b1.z,b1.w};
            #pragma unroll
            for (int j = 0; j < 8; ++j) {
                int d = d0 + j;
                bf16x2 pk = {(__bf16)av[j], (__bf16)bv[j]};
                *reinterpret_cast<bf16x2*>(VtB + d*128 + ((kv0*2) ^ ((d & 7) << 4))) = pk;
            }
        }
        __syncthreads();

        // ---- QK^T: S[q 32][kv 64] per wave; B-frag of K^T == row-major K read ----
        floatx4 s[2][4];
        #pragma unroll
        for (int nt = 0; nt < 4; ++nt) {
            s[0][nt] = (floatx4){0.f,0.f,0.f,0.f};
            s[1][nt] = (floatx4){0.f,0.f,0.f,0.f};
            int row = nt*16 + c;                  // kv row in tile
            #pragma unroll
            for (int kk = 0; kk < 2; ++kk) {
                bf16x8 bk = *reinterpret_cast<const bf16x8*>(
                    KtB + row*128 + ((g*16 + kk*64) ^ ((row & 7) << 4)));
                s[0][nt] = __builtin_amdgcn_mfma_f32_16x16x32_bf16(aq[0][kk], bk, s[0][nt], 0,0,0);
                s[1][nt] = __builtin_amdgcn_mfma_f32_16x16x32_bf16(aq[1][kk], bk, s[1][nt], 0,0,0);
            }
        }

        // ---- online softmax (rows = g*4+r per m-tile; reduce over 16-lane group) ----
        #pragma unroll
        for (int mt = 0; mt < 2; ++mt) {
            float fac[4];
            #pragma unroll
            for (int r = 0; r < 4; ++r) {
                float mx = fmaxf(fmaxf(s[mt][0][r], s[mt][1][r]),
                                 fmaxf(s[mt][2][r], s[mt][3][r]));
                mx = grp16_max(mx);
                float mnew = fmaxf(mrun[mt][r], mx);
                fac[r] = __expf(mrun[mt][r] - mnew);
                mrun[mt][r] = mnew;
            }
            float rs[4] = {0.f, 0.f, 0.f, 0.f};
            #pragma unroll
            for (int nt = 0; nt < 4; ++nt) {
                #pragma unroll
                for (int r = 0; r < 4; ++r) {
                    float p = __expf(s[mt][nt][r] - mrun[mt][r]);
                    s[mt][nt][r] = p;
                    rs[r] += p;
                }
            }
            #pragma unroll
            for (int r = 0; r < 4; ++r) {
                rs[r] = grp16_sum(rs[r]);
                lrun[mt][r] = lrun[mt][r] * fac[r] + rs[r];
                #pragma unroll
                for (int dt = 0; dt < 4; ++dt) o[mt][dt][r] *= fac[r];
            }
            // write P (bf16) to this wave's LDS buffer, swizzled
            #pragma unroll
            for (int nt = 0; nt < 4; ++nt) {
                #pragma unroll
                for (int r = 0; r < 4; ++r) {
                    int prow = mt*16 + g*4 + r;
                    *reinterpret_cast<__bf16*>(
                        PtB + prow*128 + (((nt*16 + c)*2) ^ ((prow & 7) << 4)))
                        = (__bf16)s[mt][nt][r];
                }
            }
        }
        // wave-local write->read ordering for Pt (compiler + HW fence)
        asm volatile("s_waitcnt lgkmcnt(0)" ::: "memory");

        // ---- PV: O += P(32x64) * V(64x64); A=P from LDS, B=V^T rows from LDS ----
        #pragma unroll
        for (int kk = 0; kk < 2; ++kk) {
            int r0 = c, r1 = 16 + c;
            bf16x8 ap0 = *reinterpret_cast<const bf16x8*>(
                PtB + r0*128 + ((g*16 + kk*64) ^ ((r0 & 7) << 4)));
            bf16x8 ap1 = *reinterpret_cast<const bf16x8*>(
                PtB + r1*128 + ((g*16 + kk*64) ^ ((r1 & 7) << 4)));
            #pragma unroll
            for (int dt = 0; dt < 4; ++dt) {
                int vr = dt*16 + c;
                bf16x8 bvv = *reinterpret_cast<const bf16x8*>(
                    VtB + vr*128 + ((g*16 + kk*64) ^ ((vr & 7) << 4)));
                o[0][dt] = __builtin_amdgcn_mfma_f32_16x16x32_bf16(ap0, bvv, o[0][dt], 0,0,0);
                o[1][dt] = __builtin_amdgcn_mfma_f32_16x16x32_bf16(ap1, bvv, o[1][dt], 0,0,0);
            }
        }
    }

    // ---- epilogue: O /= l, store fp32 ----
    #pragma unroll
    for (int mt = 0; mt < 2; ++mt) {
        #pragma unroll
        for (int r = 0; r < 4; ++r) {
            float inv = 1.0f / lrun[mt][r];
            size_t rowoff = ((size_t)(b*SEQ + q0 + w*QW + mt*16 + g*4 + r)) * DIM;
            #pragma unroll
            for (int dt = 0; dt < 4; ++dt)
                Out[rowoff + dt*16 + c] = o[mt][dt][r] * inv;
        }
    }
}

extern "C" void kernel_launch(void* const* d_in, const int* in_sizes, int n_in,
                              void* d_out, int out_size, void* d_ws, size_t ws_size,
                              hipStream_t stream) {
    const float* Q = (const float*)d_in[0];
    const float* K = (const float*)d_in[1];
    const float* V = (const float*)d_in[2];
    float* O = (float*)d_out;
    dim3 grid(BATCH * (SEQ / QB));   // 32 * 16 = 512
    attn_fwd<<<grid, dim3(256), 0, stream>>>(Q, K, V, O);
}

// Round 3
// 56.541 us; speedup vs baseline: 2.2432x; 2.2432x over previous
//
#include <hip/hip_runtime.h>
#include <hip/hip_bf16.h>

#define B_   32
#define S_   2048
#define D_   64
#define KVB  64
#define NT   (S_/KVB)      // 32 kv tiles
#define NW   8             // waves per block
#define QW   32            // q rows per wave
#define QB   (NW*QW)       // 256 q rows per block

typedef __attribute__((ext_vector_type(8)))  __bf16 bf16x8;
typedef __attribute__((ext_vector_type(4)))  __bf16 bf16x4;
typedef __attribute__((ext_vector_type(16))) float  f32x16;

__device__ __forceinline__ float fexp2(float x) {
#if __has_builtin(__builtin_amdgcn_exp2f)
    return __builtin_amdgcn_exp2f(x);
#else
    return exp2f(x);
#endif
}

// one VOP3: packs two f32 -> 2x bf16 in a dword (lo = a, hi = b)
__device__ __forceinline__ unsigned pk2(float a, float b) {
    unsigned r;
    asm("v_cvt_pk_bf16_f32 %0, %1, %2" : "=v"(r) : "v"(a), "v"(b));
    return r;
}

// swap a's upper-32-lane half with b's lower-32-lane half.
// after: a[l<32]=a, a[l>=32]=b[l-32]; b[l<32]=a[l+32], b[l>=32]=b.
__device__ __forceinline__ void pl32swap(unsigned &a, unsigned &b) {
#if __has_builtin(__builtin_amdgcn_permlane32_swap)
    auto r = __builtin_amdgcn_permlane32_swap(a, b, false, false);
    a = (unsigned)r[0]; b = (unsigned)r[1];
#else
    unsigned pa = (unsigned)__shfl_xor((int)a, 32);
    unsigned pb = (unsigned)__shfl_xor((int)b, 32);
    bool hi = (threadIdx.x & 32) != 0;
    unsigned na = hi ? pb : a;
    unsigned nb = hi ? b  : pa;
    a = na; b = nb;
#endif
}

__device__ __forceinline__ f32x16 z16() {
    f32x16 z;
    #pragma unroll
    for (int i = 0; i < 16; ++i) z[i] = 0.f;
    return z;
}

struct PBpair { bf16x8 a, b; };

// Build two PV B-fragments (kv chunks of 16) from one 32-kv score tile.
// Lane layout in: ps[r] = P[q=lane&31][kv32 = (r&3)+8*(r>>2)+4*(lane>>5)].
__device__ __forceinline__ PBpair pack2(const f32x16 ps) {
    unsigned y0 = pk2(ps[0],  ps[1]);
    unsigned y1 = pk2(ps[2],  ps[3]);
    unsigned y2 = pk2(ps[4],  ps[5]);
    unsigned y3 = pk2(ps[6],  ps[7]);
    pl32swap(y0, y2); pl32swap(y1, y3);      // -> W0,W2 / W1,W3 of chunk even
    unsigned z0 = pk2(ps[8],  ps[9]);
    unsigned z1 = pk2(ps[10], ps[11]);
    unsigned z2 = pk2(ps[12], ps[13]);
    unsigned z3 = pk2(ps[14], ps[15]);
    pl32swap(z0, z2); pl32swap(z1, z3);      // chunk odd
    union { unsigned u[4]; bf16x8 v; } pa, pbu;
    pa.u[0]=y0;  pa.u[1]=y1;  pa.u[2]=y2;  pa.u[3]=y3;
    pbu.u[0]=z0; pbu.u[1]=z1; pbu.u[2]=z2; pbu.u[3]=z3;
    PBpair r; r.a = pa.v; r.b = pbu.v; return r;
}

__global__ __launch_bounds__(512, 2)
void attn_fwd(const float* __restrict__ Q, const float* __restrict__ K,
              const float* __restrict__ V, float* __restrict__ Out)
{
    // double-buffered K (row-major, XOR-swizzled) and V^T tiles; 32 KiB total
    __shared__ __align__(16) __bf16 Kt[2][KVB * D_];
    __shared__ __align__(16) __bf16 Vt[2][D_ * KVB];

    const int tid  = threadIdx.x;
    const int w    = tid >> 6;
    const int lane = tid & 63;
    const int l31  = lane & 31;
    const int hi   = lane >> 5;

    const int bid = blockIdx.x;
    const int swz = ((bid & 7) << 5) | (bid >> 3);   // bijective XCD swizzle (256 blocks)
    const int b   = swz >> 3;                        // batch: 4 consecutive per XCD
    const int q0  = (swz & 7) * QB;

    // ---- Q fragments: B-operand of K·Q^T; scale (1/8)*log2(e) folded in ----
    const float SCL = 0.18033688011112042f;
    const float* qp = Q + ((size_t)(b*S_ + q0 + w*QW + l31))*D_ + hi*8;
    bf16x8 qf[4];
    #pragma unroll
    for (int ks = 0; ks < 4; ++ks) {
        float4 f0 = *reinterpret_cast<const float4*>(qp + ks*16);
        float4 f1 = *reinterpret_cast<const float4*>(qp + ks*16 + 4);
        bf16x8 a;
        a[0]=(__bf16)(f0.x*SCL); a[1]=(__bf16)(f0.y*SCL);
        a[2]=(__bf16)(f0.z*SCL); a[3]=(__bf16)(f0.w*SCL);
        a[4]=(__bf16)(f1.x*SCL); a[5]=(__bf16)(f1.y*SCL);
        a[6]=(__bf16)(f1.z*SCL); a[7]=(__bf16)(f1.w*SCL);
        qf[ks]=a;
    }

    // per-lane LDS read offsets (shared formula for K rows and V^T rows)
    const int swzk = (l31 & 7) << 4;
    int offK[4];
    #pragma unroll
    for (int i = 0; i < 4; ++i)
        offK[i] = l31*128 + (((i*32) + hi*16) ^ swzk);

    // ---- staging geometry ----
    const float* kg = K + (size_t)b*S_*D_;
    const float* vg = V + (size_t)b*S_*D_;

    const int krow0 = tid >> 4;                 // 0..31 (and +32)
    const int kcol  = (tid & 15) * 4;           // float col
    const int kwr0  = krow0*128 + ((kcol*2) ^ ((krow0 & 7) << 4));
    const int kwr1  = kwr0 + 32*128;

    const int kv0 = (tid >> 4) * 2;             // 0..62
    const int db  = (tid & 15) * 2;             // 0..30
    int vwr[4];
    #pragma unroll
    for (int j = 0; j < 4; ++j) {
        int d = db + (j >> 1)*32 + (j & 1);     // db, db+1, db+32, db+33
        vwr[j] = d*128 + ((kv0*2) ^ ((d & 7) << 4));
    }

    // ---- prologue: stage tile 0 into buffer 0 ----
    {
        float4 ka  = *reinterpret_cast<const float4*>(kg + krow0*64 + kcol);
        float4 kb  = *reinterpret_cast<const float4*>(kg + (krow0+32)*64 + kcol);
        float2 va0 = *reinterpret_cast<const float2*>(vg + kv0*64 + db);
        float2 vb0 = *reinterpret_cast<const float2*>(vg + (kv0+1)*64 + db);
        float2 va1 = *reinterpret_cast<const float2*>(vg + kv0*64 + db + 32);
        float2 vb1 = *reinterpret_cast<const float2*>(vg + (kv0+1)*64 + db + 32);
        char* kw = (char*)&Kt[0][0];
        char* vw = (char*)&Vt[0][0];
        bf16x4 h0 = {(__bf16)ka.x,(__bf16)ka.y,(__bf16)ka.z,(__bf16)ka.w};
        bf16x4 h1 = {(__bf16)kb.x,(__bf16)kb.y,(__bf16)kb.z,(__bf16)kb.w};
        *reinterpret_cast<bf16x4*>(kw + kwr0) = h0;
        *reinterpret_cast<bf16x4*>(kw + kwr1) = h1;
        *reinterpret_cast<unsigned*>(vw + vwr[0]) = pk2(va0.x, vb0.x);
        *reinterpret_cast<unsigned*>(vw + vwr[1]) = pk2(va0.y, vb0.y);
        *reinterpret_cast<unsigned*>(vw + vwr[2]) = pk2(va1.x, vb1.x);
        *reinterpret_cast<unsigned*>(vw + vwr[3]) = pk2(va1.y, vb1.y);
    }
    __syncthreads();

    float m_ = -INFINITY, l_ = 0.f;
    f32x16 o0 = z16(), o1 = z16();

    #pragma unroll 2
    for (int t = 0; t < NT; ++t) {
        const int cur = t & 1;

        // -- issue next-tile global loads early (hide HBM under compute) --
        const int tn = (t+1 < NT) ? (t+1) : t;
        const float* kt_ = kg + tn*KVB*D_;
        const float* vt_ = vg + tn*KVB*D_;
        float4 ka  = *reinterpret_cast<const float4*>(kt_ + krow0*64 + kcol);
        float4 kb  = *reinterpret_cast<const float4*>(kt_ + (krow0+32)*64 + kcol);
        float2 va0 = *reinterpret_cast<const float2*>(vt_ + kv0*64 + db);
        float2 vb0 = *reinterpret_cast<const float2*>(vt_ + (kv0+1)*64 + db);
        float2 va1 = *reinterpret_cast<const float2*>(vt_ + kv0*64 + db + 32);
        float2 vb1 = *reinterpret_cast<const float2*>(vt_ + (kv0+1)*64 + db + 32);

        const char* kbuf = (const char*)&Kt[cur][0];
        const char* vbuf = (const char*)&Vt[cur][0];

        // -- QK^T (swapped): S^T[kv][q], kv-subtiles 0-31 / 32-63 --
        f32x16 s0 = z16(), s1 = z16();
        __builtin_amdgcn_s_setprio(1);
        #pragma unroll
        for (int ks = 0; ks < 4; ++ks) {
            bf16x8 k0 = *reinterpret_cast<const bf16x8*>(kbuf + offK[ks]);
            bf16x8 k1 = *reinterpret_cast<const bf16x8*>(kbuf + offK[ks] + 4096);
            s0 = __builtin_amdgcn_mfma_f32_32x32x16_bf16(k0, qf[ks], s0, 0,0,0);
            s1 = __builtin_amdgcn_mfma_f32_32x32x16_bf16(k1, qf[ks], s1, 0,0,0);
        }
        __builtin_amdgcn_s_setprio(0);

        // -- in-register online softmax (base-2), q = lane&31 --
        float pmax = s0[0];
        #pragma unroll
        for (int r = 1; r < 16; ++r) pmax = fmaxf(pmax, s0[r]);
        #pragma unroll
        for (int r = 0; r < 16; ++r) pmax = fmaxf(pmax, s1[r]);
        pmax = fmaxf(pmax, __shfl_xor(pmax, 32));
        if (!__all(pmax - m_ <= 8.0f)) {        // defer-max (T13), P <= 2^8
            float mn  = fmaxf(m_, pmax);
            float fac = fexp2(m_ - mn);
            m_ = mn; l_ *= fac;
            #pragma unroll
            for (int r = 0; r < 16; ++r) { o0[r] *= fac; o1[r] *= fac; }
        }
        float lsum = 0.f;
        #pragma unroll
        for (int r = 0; r < 16; ++r) { s0[r] = fexp2(s0[r] - m_); lsum += s0[r]; }
        #pragma unroll
        for (int r = 0; r < 16; ++r) { s1[r] = fexp2(s1[r] - m_); lsum += s1[r]; }
        lsum += __shfl_xor(lsum, 32);
        l_ += lsum;

        // -- P -> bf16 B-fragments, fully in-register (T12) --
        PBpair p01 = pack2(s0);   // kv chunks 0,1
        PBpair p23 = pack2(s1);   // kv chunks 2,3

        // -- PV: O^T[d][q] += V^T · P^T --
        __builtin_amdgcn_s_setprio(1);
        #define PV_STEP(c, pbf)                                                        \
        {   bf16x8 v0 = *reinterpret_cast<const bf16x8*>(vbuf + offK[c]);              \
            bf16x8 v1 = *reinterpret_cast<const bf16x8*>(vbuf + offK[c] + 4096);       \
            o0 = __builtin_amdgcn_mfma_f32_32x32x16_bf16(v0, pbf, o0, 0,0,0);          \
            o1 = __builtin_amdgcn_mfma_f32_32x32x16_bf16(v1, pbf, o1, 0,0,0);          }
        PV_STEP(0, p01.a)
        PV_STEP(1, p01.b)
        PV_STEP(2, p23.a)
        PV_STEP(3, p23.b)
        #undef PV_STEP
        __builtin_amdgcn_s_setprio(0);

        // -- write staged tile t+1 into the other buffer (vmcnt drains here) --
        if (t+1 < NT) {
            char* kw = (char*)&Kt[cur^1][0];
            char* vw = (char*)&Vt[cur^1][0];
            bf16x4 h0 = {(__bf16)ka.x,(__bf16)ka.y,(__bf16)ka.z,(__bf16)ka.w};
            bf16x4 h1 = {(__bf16)kb.x,(__bf16)kb.y,(__bf16)kb.z,(__bf16)kb.w};
            *reinterpret_cast<bf16x4*>(kw + kwr0) = h0;
            *reinterpret_cast<bf16x4*>(kw + kwr1) = h1;
            *reinterpret_cast<unsigned*>(vw + vwr[0]) = pk2(va0.x, vb0.x);
            *reinterpret_cast<unsigned*>(vw + vwr[1]) = pk2(va0.y, vb0.y);
            *reinterpret_cast<unsigned*>(vw + vwr[2]) = pk2(va1.x, vb1.x);
            *reinterpret_cast<unsigned*>(vw + vwr[3]) = pk2(va1.y, vb1.y);
        }
        __syncthreads();
    }

    // ---- epilogue: O = O^T-normalized; lane owns q-row, d = (r&3)+8*(r>>2)+4*hi ----
    float invl = 1.0f / l_;
    float* orow = Out + ((size_t)(b*S_ + q0 + w*QW + l31))*D_;
    #pragma unroll
    for (int rr = 0; rr < 4; ++rr) {
        float4 res;
        res.x = o0[rr*4+0]*invl; res.y = o0[rr*4+1]*invl;
        res.z = o0[rr*4+2]*invl; res.w = o0[rr*4+3]*invl;
        *reinterpret_cast<float4*>(orow + rr*8 + hi*4) = res;
    }
    #pragma unroll
    for (int rr = 0; rr < 4; ++rr) {
        float4 res;
        res.x = o1[rr*4+0]*invl; res.y = o1[rr*4+1]*invl;
        res.z = o1[rr*4+2]*invl; res.w = o1[rr*4+3]*invl;
        *reinterpret_cast<float4*>(orow + 32 + rr*8 + hi*4) = res;
    }
}

extern "C" void kernel_launch(void* const* d_in, const int* in_sizes, int n_in,
                              void* d_out, int out_size, void* d_ws, size_t ws_size,
                              hipStream_t stream) {
    const float* Q = (const float*)d_in[0];
    const float* K = (const float*)d_in[1];
    const float* V = (const float*)d_in[2];
    float* O = (float*)d_out;
    attn_fwd<<<dim3(B_ * (S_ / QB)), dim3(512), 0, stream>>>(Q, K, V, O);
}

// Round 4
// 56.424 us; speedup vs baseline: 2.2479x; 1.0021x over previous
//
#include <hip/hip_runtime.h>
#include <hip/hip_bf16.h>

#define B_   32
#define S_   2048
#define D_   64
#define KVB  64
#define NT   (S_/KVB)      // 32 kv tiles
#define NW   8             // waves per block
#define QW   32            // q rows per wave
#define QB   (NW*QW)       // 256 q rows per block

typedef __attribute__((ext_vector_type(8)))  __bf16 bf16x8;
typedef __attribute__((ext_vector_type(4)))  __bf16 bf16x4;
typedef __attribute__((ext_vector_type(16))) float  f32x16;

__device__ __forceinline__ float fexp2(float x) {
#if __has_builtin(__builtin_amdgcn_exp2f)
    return __builtin_amdgcn_exp2f(x);
#else
    return exp2f(x);
#endif
}

// one VOP3: packs two f32 -> 2x bf16 in a dword (lo = a, hi = b)
__device__ __forceinline__ unsigned pk2(float a, float b) {
    unsigned r;
    asm("v_cvt_pk_bf16_f32 %0, %1, %2" : "=v"(r) : "v"(a), "v"(b));
    return r;
}

// swap a's upper-32-lane half with b's lower-32-lane half.
// after: a[l<32]=a, a[l>=32]=b[l-32]; b[l<32]=a[l+32], b[l>=32]=b.
__device__ __forceinline__ void pl32swap(unsigned &a, unsigned &b) {
#if __has_builtin(__builtin_amdgcn_permlane32_swap)
    auto r = __builtin_amdgcn_permlane32_swap(a, b, false, false);
    a = (unsigned)r[0]; b = (unsigned)r[1];
#else
    unsigned pa = (unsigned)__shfl_xor((int)a, 32);
    unsigned pb = (unsigned)__shfl_xor((int)b, 32);
    bool hi = (threadIdx.x & 32) != 0;
    unsigned na = hi ? pb : a;
    unsigned nb = hi ? b  : pa;
    a = na; b = nb;
#endif
}

__device__ __forceinline__ f32x16 z16() {
    f32x16 z;
    #pragma unroll
    for (int i = 0; i < 16; ++i) z[i] = 0.f;
    return z;
}

struct PBpair { bf16x8 a, b; };

// Build two PV B-fragments (kv chunks of 16) from one 32-kv score tile.
// Lane layout in: ps[r] = P[q=lane&31][kv32 = (r&3)+8*(r>>2)+4*(lane>>5)].
__device__ __forceinline__ PBpair pack2(const f32x16 ps) {
    unsigned y0 = pk2(ps[0],  ps[1]);
    unsigned y1 = pk2(ps[2],  ps[3]);
    unsigned y2 = pk2(ps[4],  ps[5]);
    unsigned y3 = pk2(ps[6],  ps[7]);
    pl32swap(y0, y2); pl32swap(y1, y3);      // -> W0,W2 / W1,W3 of chunk even
    unsigned z0 = pk2(ps[8],  ps[9]);
    unsigned z1 = pk2(ps[10], ps[11]);
    unsigned z2 = pk2(ps[12], ps[13]);
    unsigned z3 = pk2(ps[14], ps[15]);
    pl32swap(z0, z2); pl32swap(z1, z3);      // chunk odd
    union { unsigned u[4]; bf16x8 v; } pa, pbu;
    pa.u[0]=y0;  pa.u[1]=y1;  pa.u[2]=y2;  pa.u[3]=y3;
    pbu.u[0]=z0; pbu.u[1]=z1; pbu.u[2]=z2; pbu.u[3]=z3;
    PBpair r; r.a = pa.v; r.b = pbu.v; return r;
}

__global__ __launch_bounds__(512, 2)
void attn_fwd(const float* __restrict__ Q, const float* __restrict__ K,
              const float* __restrict__ V, float* __restrict__ Out)
{
    // double-buffered K (row-major, XOR-swizzled) and V^T tiles; 32 KiB total
    __shared__ __align__(16) __bf16 Kt[2][KVB * D_];
    __shared__ __align__(16) __bf16 Vt[2][D_ * KVB];

    const int tid  = threadIdx.x;
    const int w    = tid >> 6;
    const int lane = tid & 63;
    const int l31  = lane & 31;
    const int hi   = lane >> 5;

    const int bid = blockIdx.x;
    const int swz = ((bid & 7) << 5) | (bid >> 3);   // bijective XCD swizzle (256 blocks)
    const int b   = swz >> 3;                        // batch: 4 consecutive per XCD
    const int q0  = (swz & 7) * QB;

    // ---- Q fragments: B-operand of K·Q^T; scale (1/8)*log2(e) folded in ----
    const float SCL = 0.18033688011112042f;
    const float* qp = Q + ((size_t)(b*S_ + q0 + w*QW + l31))*D_ + hi*8;
    bf16x8 qf[4];
    #pragma unroll
    for (int ks = 0; ks < 4; ++ks) {
        float4 f0 = *reinterpret_cast<const float4*>(qp + ks*16);
        float4 f1 = *reinterpret_cast<const float4*>(qp + ks*16 + 4);
        bf16x8 a;
        a[0]=(__bf16)(f0.x*SCL); a[1]=(__bf16)(f0.y*SCL);
        a[2]=(__bf16)(f0.z*SCL); a[3]=(__bf16)(f0.w*SCL);
        a[4]=(__bf16)(f1.x*SCL); a[5]=(__bf16)(f1.y*SCL);
        a[6]=(__bf16)(f1.z*SCL); a[7]=(__bf16)(f1.w*SCL);
        qf[ks]=a;
    }

    // per-lane LDS read offsets (shared formula for K rows and V^T rows)
    const int swzk = (l31 & 7) << 4;
    int offK[4];
    #pragma unroll
    for (int i = 0; i < 4; ++i)
        offK[i] = l31*128 + (((i*32) + hi*16) ^ swzk);

    // ---- staging geometry ----
    const float* kg = K + (size_t)b*S_*D_;
    const float* vg = V + (size_t)b*S_*D_;

    const int krow0 = tid >> 4;                 // 0..31 (and +32)
    const int kcol  = (tid & 15) * 4;           // float col
    const int kwr0  = krow0*128 + ((kcol*2) ^ ((krow0 & 7) << 4));
    const int kwr1  = kwr0 + 32*128;

    const int kv0 = (tid >> 4) * 2;             // 0..62
    const int db  = (tid & 15) * 2;             // 0..30
    int vwr[4];
    #pragma unroll
    for (int j = 0; j < 4; ++j) {
        int d = db + (j >> 1)*32 + (j & 1);     // db, db+1, db+32, db+33
        vwr[j] = d*128 + ((kv0*2) ^ ((d & 7) << 4));
    }

    // ---- prologue: stage tile 0 into buffer 0 ----
    {
        float4 ka  = *reinterpret_cast<const float4*>(kg + krow0*64 + kcol);
        float4 kb  = *reinterpret_cast<const float4*>(kg + (krow0+32)*64 + kcol);
        float2 va0 = *reinterpret_cast<const float2*>(vg + kv0*64 + db);
        float2 vb0 = *reinterpret_cast<const float2*>(vg + (kv0+1)*64 + db);
        float2 va1 = *reinterpret_cast<const float2*>(vg + kv0*64 + db + 32);
        float2 vb1 = *reinterpret_cast<const float2*>(vg + (kv0+1)*64 + db + 32);
        char* kw = (char*)&Kt[0][0];
        char* vw = (char*)&Vt[0][0];
        bf16x4 h0 = {(__bf16)ka.x,(__bf16)ka.y,(__bf16)ka.z,(__bf16)ka.w};
        bf16x4 h1 = {(__bf16)kb.x,(__bf16)kb.y,(__bf16)kb.z,(__bf16)kb.w};
        *reinterpret_cast<bf16x4*>(kw + kwr0) = h0;
        *reinterpret_cast<bf16x4*>(kw + kwr1) = h1;
        *reinterpret_cast<unsigned*>(vw + vwr[0]) = pk2(va0.x, vb0.x);
        *reinterpret_cast<unsigned*>(vw + vwr[1]) = pk2(va0.y, vb0.y);
        *reinterpret_cast<unsigned*>(vw + vwr[2]) = pk2(va1.x, vb1.x);
        *reinterpret_cast<unsigned*>(vw + vwr[3]) = pk2(va1.y, vb1.y);
    }
    __syncthreads();

    float m_ = -INFINITY, l_ = 0.f;
    f32x16 o0 = z16(), o1 = z16();

    #pragma unroll 2
    for (int t = 0; t < NT; ++t) {
        const int cur = t & 1;

        // -- issue next-tile global loads early (hide HBM under compute) --
        const int tn = (t+1 < NT) ? (t+1) : t;
        const float* kt_ = kg + tn*KVB*D_;
        const float* vt_ = vg + tn*KVB*D_;
        float4 ka  = *reinterpret_cast<const float4*>(kt_ + krow0*64 + kcol);
        float4 kb  = *reinterpret_cast<const float4*>(kt_ + (krow0+32)*64 + kcol);
        float2 va0 = *reinterpret_cast<const float2*>(vt_ + kv0*64 + db);
        float2 vb0 = *reinterpret_cast<const float2*>(vt_ + (kv0+1)*64 + db);
        float2 va1 = *reinterpret_cast<const float2*>(vt_ + kv0*64 + db + 32);
        float2 vb1 = *reinterpret_cast<const float2*>(vt_ + (kv0+1)*64 + db + 32);

        const char* kbuf = (const char*)&Kt[cur][0];
        const char* vbuf = (const char*)&Vt[cur][0];

        // -- QK^T (swapped): S^T[kv][q], kv-subtiles 0-31 / 32-63 --
        f32x16 s0 = z16(), s1 = z16();
        __builtin_amdgcn_s_setprio(1);
        #pragma unroll
        for (int ks = 0; ks < 4; ++ks) {
            bf16x8 k0 = *reinterpret_cast<const bf16x8*>(kbuf + offK[ks]);
            bf16x8 k1 = *reinterpret_cast<const bf16x8*>(kbuf + offK[ks] + 4096);
            s0 = __builtin_amdgcn_mfma_f32_32x32x16_bf16(k0, qf[ks], s0, 0,0,0);
            s1 = __builtin_amdgcn_mfma_f32_32x32x16_bf16(k1, qf[ks], s1, 0,0,0);
        }
        __builtin_amdgcn_s_setprio(0);

        // -- in-register online softmax (base-2), q = lane&31 --
        float pmax = s0[0];
        #pragma unroll
        for (int r = 1; r < 16; ++r) pmax = fmaxf(pmax, s0[r]);
        #pragma unroll
        for (int r = 0; r < 16; ++r) pmax = fmaxf(pmax, s1[r]);
        pmax = fmaxf(pmax, __shfl_xor(pmax, 32));
        if (!__all(pmax - m_ <= 8.0f)) {        // defer-max (T13), P <= 2^8
            float mn  = fmaxf(m_, pmax);
            float fac = fexp2(m_ - mn);
            m_ = mn; l_ *= fac;
            #pragma unroll
            for (int r = 0; r < 16; ++r) { o0[r] *= fac; o1[r] *= fac; }
        }
        float lsum = 0.f;
        #pragma unroll
        for (int r = 0; r < 16; ++r) { s0[r] = fexp2(s0[r] - m_); lsum += s0[r]; }
        #pragma unroll
        for (int r = 0; r < 16; ++r) { s1[r] = fexp2(s1[r] - m_); lsum += s1[r]; }
        lsum += __shfl_xor(lsum, 32);
        l_ += lsum;

        // -- P -> bf16 B-fragments, fully in-register (T12) --
        PBpair p01 = pack2(s0);   // kv chunks 0,1
        PBpair p23 = pack2(s1);   // kv chunks 2,3

        // -- PV: O^T[d][q] += V^T · P^T --
        __builtin_amdgcn_s_setprio(1);
        #define PV_STEP(c, pbf)                                                        \
        {   bf16x8 v0 = *reinterpret_cast<const bf16x8*>(vbuf + offK[c]);              \
            bf16x8 v1 = *reinterpret_cast<const bf16x8*>(vbuf + offK[c] + 4096);       \
            o0 = __builtin_amdgcn_mfma_f32_32x32x16_bf16(v0, pbf, o0, 0,0,0);          \
            o1 = __builtin_amdgcn_mfma_f32_32x32x16_bf16(v1, pbf, o1, 0,0,0);          }
        PV_STEP(0, p01.a)
        PV_STEP(1, p01.b)
        PV_STEP(2, p23.a)
        PV_STEP(3, p23.b)
        #undef PV_STEP
        __builtin_amdgcn_s_setprio(0);

        // -- write staged tile t+1 into the other buffer (vmcnt drains here) --
        if (t+1 < NT) {
            char* kw = (char*)&Kt[cur^1][0];
            char* vw = (char*)&Vt[cur^1][0];
            bf16x4 h0 = {(__bf16)ka.x,(__bf16)ka.y,(__bf16)ka.z,(__bf16)ka.w};
            bf16x4 h1 = {(__bf16)kb.x,(__bf16)kb.y,(__bf16)kb.z,(__bf16)kb.w};
            *reinterpret_cast<bf16x4*>(kw + kwr0) = h0;
            *reinterpret_cast<bf16x4*>(kw + kwr1) = h1;
            *reinterpret_cast<unsigned*>(vw + vwr[0]) = pk2(va0.x, vb0.x);
            *reinterpret_cast<unsigned*>(vw + vwr[1]) = pk2(va0.y, vb0.y);
            *reinterpret_cast<unsigned*>(vw + vwr[2]) = pk2(va1.x, vb1.x);
            *reinterpret_cast<unsigned*>(vw + vwr[3]) = pk2(va1.y, vb1.y);
        }
        __syncthreads();
    }

    // ---- epilogue: O = O^T-normalized; lane owns q-row, d = (r&3)+8*(r>>2)+4*hi ----
    float invl = 1.0f / l_;
    float* orow = Out + ((size_t)(b*S_ + q0 + w*QW + l31))*D_;
    #pragma unroll
    for (int rr = 0; rr < 4; ++rr) {
        float4 res;
        res.x = o0[rr*4+0]*invl; res.y = o0[rr*4+1]*invl;
        res.z = o0[rr*4+2]*invl; res.w = o0[rr*4+3]*invl;
        *reinterpret_cast<float4*>(orow + rr*8 + hi*4) = res;
    }
    #pragma unroll
    for (int rr = 0; rr < 4; ++rr) {
        float4 res;
        res.x = o1[rr*4+0]*invl; res.y = o1[rr*4+1]*invl;
        res.z = o1[rr*4+2]*invl; res.w = o1[rr*4+3]*invl;
        *reinterpret_cast<float4*>(orow + 32 + rr*8 + hi*4) = res;
    }
}

extern "C" void kernel_launch(void* const* d_in, const int* in_sizes, int n_in,
                              void* d_out, int out_size, void* d_ws, size_t ws_size,
                              hipStream_t stream) {
    const float* Q = (const float*)d_in[0];
    const float* K = (const float*)d_in[1];
    const float* V = (const float*)d_in[2];
    float* O = (float*)d_out;
    attn_fwd<<<dim3(B_ * (S_ / QB)), dim3(512), 0, stream>>>(Q, K, V, O);
}